// Round 14
// baseline (211.365 us; speedup 1.0000x reference)
//
#include <hip/hip_runtime.h>
#include <stdint.h>

#define NINPUTS   1024
#define NOUTPUTS  1024
#define NMID      31          // middle layers
#define NN        4096        // neurons per layer
#define W         65536      // bit-array width
#define CHUNK     64          // columns per chunk: one 64-bit ballot packs a row
#define NCHUNKS   (W / CHUNK) // 1024
#define GRID      512         // 2 WGs per CU
#define CPW       (NCHUNKS / GRID)   // 2 chunks per WG, pipelined
#define THREADS   1024
#define NPAIRS    16          // fused layer-pairs (L0,L1)..(L30,L31); L32 single
#define TBL_BYTES ((size_t)NPAIRS * NN * 16)

// LDS map (80 KiB/WG -> 2 WGs/CU on the 160 KiB pool):
//   P  AoS uint2 rows (1024x8B)       [    0,  8192)
//   X  SoA 2 planes of 16 KiB         [ 8192, 40960)   plane1 = plane0+16384
//   Y  SoA 2 planes of 16 KiB         [40960, 73728)
//   R  AoS uint2 rows (1024x8B)       [73728, 81920)
// SoA: word w of row r at planeW + r*4 -> start bank = (r+c) mod 32, uniform
// over all 32 banks (AoS 8/16B rows alias to 16/8 bank classes — the
// structural conflict all rounds <=R13 carried). ds_read2st64_b32
// offset0:0 offset1:64 reads BOTH planes in one op (64*256B = 16384B apart).
#define PB  0u
#define X0B 8192u
#define Y0B 40960u
#define RB  73728u

// one-op two-plane read: lo <- [va], hi <- [va+16384]
#define SOA_READ2(DST, VA)                                                   \
    asm volatile("ds_read2st64_b32 %0, %1 offset0:0 offset1:64"              \
                 : "=v"(DST) : "v"(VA))
// one-op two-plane write
#define SOA_WRITE2(VA, LO, HI)                                               \
    asm volatile("ds_write2st64_b32 %0, %1, %2 offset0:0 offset1:64"         \
                 :: "v"(VA), "v"(LO), "v"(HI))

// Light barrier (R13: verified correct, perf-neutral at 1 WG/CU): orders LDS
// (lgkmcnt 0) without draining vmcnt — global stores/loads stay in flight.
#define LIGHT_BARRIER() asm volatile("s_waitcnt lgkmcnt(0)\n\ts_barrier" ::: "memory")

// ---------------------------------------------------------------------------
// Prep kernel. Pair F computes layer 2F+1 from layer 2F's input state:
//   r = (((s[a1]&s[b1])^m1) & ((s[a2]&s[b2])^m2)) ^ m3
// Offsets: F==0 -> P AoS (row*8); F>=1 -> plane-relative SoA (row*4).
// Entry: e.x = a1off|m1<<31; e.y = b1off; e.z = a2off|m2<<31; e.w = b2off|m3<<31.
// ---------------------------------------------------------------------------
__global__ void build_tbl_kernel(const int*      __restrict__ idx_first,
                                 const uint32_t* __restrict__ mask_first,
                                 const int*      __restrict__ idx_mid,
                                 const uint32_t* __restrict__ mask_mid,
                                 uint4*          __restrict__ tbl)
{
    const int tid = blockIdx.x * blockDim.x + threadIdx.x;   // 0..65535
    const int F = tid >> 12;
    const int n = tid & (NN - 1);

    const int*      i1;
    const uint32_t* m1;
    if (F == 0) { i1 = idx_first; m1 = mask_first; }
    else        { i1 = idx_mid + (size_t)(2 * F - 1) * NN * 2;
                  m1 = mask_mid + (size_t)(2 * F - 1) * NN; }
    const int*      i2 = idx_mid + (size_t)(2 * F) * NN * 2;
    const uint32_t* m2 = mask_mid + (size_t)(2 * F) * NN;

    const uint32_t scale = (F == 0) ? 8u : 4u;
    const int j = i2[2 * n];
    const int k = i2[2 * n + 1];
    uint4 e;
    e.x = (uint32_t)i1[2 * j]     * scale | (m1[j] ? 0x80000000u : 0u);
    e.y = (uint32_t)i1[2 * j + 1] * scale;
    e.z = (uint32_t)i1[2 * k]     * scale | (m1[k] ? 0x80000000u : 0u);
    e.w = (uint32_t)i1[2 * k + 1] * scale | (m2[n] ? 0x80000000u : 0u);
    tbl[(size_t)F * NN + n] = e;
}

// ---------------------------------------------------------------------------
// Main kernel: 17 fused rounds/chunk, pipelined pack/unpack (R8 schedule),
// 64-col chunks, SoA state, 2 WGs/CU.
// XCD pairing: blocks b and b^8 land on the same XCD (blockIdx %8 round-
// robin); they are assigned the two adjacent 64-col halves of each 512B
// global block so the per-XCD L2 merges their 256B bursts (R4 showed split
// 256B bursts across XCDs amplify HBM traffic ~3x).
// ---------------------------------------------------------------------------
__global__ __launch_bounds__(THREADS, 8)
void nand_fused_kernel(const uint32_t* __restrict__ in,         // [1024][W]
                       const uint4*    __restrict__ tbl,        // [16][NN]
                       const int*      __restrict__ idx_last,   // [NOUTPUTS][2]
                       const uint32_t* __restrict__ mask_last,  // [NOUTPUTS]
                       uint32_t*       __restrict__ out)        // [NOUTPUTS][W]
{
    __shared__ uint32_t lds[20480];          // 80 KiB
    uint32_t* P = lds;                       // AoS uint2 rows
    uint32_t* R = lds + (RB / 4);            // AoS uint2 rows

    const int t  = threadIdx.x;
    const int l  = t & 63;
    const int wv = t >> 6;                   // wave 0..15
    const int lane32 = l & 31;

    // XCD-paired chunk mapping (bijective): b -> (xcd, j, h)
    const int b      = blockIdx.x;
    const int xcd    = b & 7;
    const int jj     = b >> 4;               // 0..31
    const int hh     = (b >> 3) & 1;         // which half of the 512B block
    const int pairid = xcd * 32 + jj;        // 0..255
    const int chunk0 = 2 * pairid + hh;      // phase-0 chunk, 0..511
    // phase-i chunk = chunk0 + 512*i ; c0 = chunk*64

    // ---------------- prologue: pack chunk(0) fully into P ----------------
    {
        const int c0 = chunk0 * CHUNK;
        #pragma unroll 4
        for (int s = 0; s < 16; ++s) {
            #pragma unroll
            for (int q = 0; q < 4; ++q) {
                const int r = s * 64 + wv * 4 + q;
                const uint32_t v = in[(size_t)r * W + c0 + l];
                const unsigned long long bb = __ballot(v != 0u);
                if (l == 0) {
                    uint2 w;
                    w.x = (uint32_t)bb;
                    w.y = (uint32_t)(bb >> 32);
                    *(uint2*)&P[r * 2] = w;
                }
            }
        }
    }
    __syncthreads();

    for (int i = 0; i < CPW; ++i) {
        const int c0n = (chunk0 + 512 * (i + 1)) * CHUNK;   // pack source cols
        const int c0p = (chunk0 + 512 * (i - 1)) * CHUNK;   // unpack dest cols
        const bool do_pack   = (i + 1 < CPW);
        const bool do_unpack = (i > 0);

        for (int F = 0; F <= 16; ++F) {
            // ---- (a) global loads at round top ----
            uint32_t pv[4];
            int prow = 0;
            if (do_pack && F >= 1) {
                prow = (F - 1) * 64 + wv * 4;
                #pragma unroll
                for (int q = 0; q < 4; ++q)
                    pv[q] = in[(size_t)(prow + q) * W + c0n + l];
            }
            uint4 tc[4];
            if (F <= 15) {
                #pragma unroll
                for (int k = 0; k < 4; ++k)
                    tc[k] = tbl[(size_t)F * NN + k * THREADS + t];
            }

            // ---- (b) gather-NAND ----
            if (F == 0) {
                // P (AoS uint2) -> X (SoA planes)
                #pragma unroll
                for (int k = 0; k < 4; ++k) {
                    const int n = k * THREADS + t;
                    const uint4 e = tc[k];
                    const uint32_t xm1 = (uint32_t)((int32_t)e.x >> 31);
                    const uint32_t xm2 = (uint32_t)((int32_t)e.z >> 31);
                    const uint32_t xm3 = (uint32_t)((int32_t)e.w >> 31);
                    const uint2 a = *(const uint2*)((const char*)lds + PB + (e.x & 0xFFFFu));
                    const uint2 bb = *(const uint2*)((const char*)lds + PB + e.y);
                    const uint2 c = *(const uint2*)((const char*)lds + PB + (e.z & 0xFFFFu));
                    const uint2 d = *(const uint2*)((const char*)lds + PB + (e.w & 0xFFFFu));
                    const uint32_t r0 = (((a.x & bb.x) ^ xm1) & ((c.x & d.x) ^ xm2)) ^ xm3;
                    const uint32_t r1 = (((a.y & bb.y) ^ xm1) & ((c.y & d.y) ^ xm2)) ^ xm3;
                    SOA_WRITE2(X0B + (uint32_t)n * 4u, r0, r1);
                }
            } else if (F <= 15) {
                const uint32_t sb0 = (F & 1) ? X0B : Y0B;   // odd F: X -> Y
                const uint32_t db0 = (F & 1) ? Y0B : X0B;
                uint64_t A[4], B[4], C[4], D[4];
                #pragma unroll
                for (int k = 0; k < 4; ++k) {
                    const uint4 e = tc[k];
                    SOA_READ2(A[k], sb0 + (e.x & 0xFFFFu));
                    SOA_READ2(B[k], sb0 + e.y);
                    SOA_READ2(C[k], sb0 + (e.z & 0xFFFFu));
                    SOA_READ2(D[k], sb0 + (e.w & 0xFFFFu));
                }
                // single drain point + fence (rule #18; R10's mistake was
                // draining per neuron)
                asm volatile("s_waitcnt lgkmcnt(0)" ::: "memory");
                __builtin_amdgcn_sched_barrier(0);
                #pragma unroll
                for (int k = 0; k < 4; ++k) {
                    const int n = k * THREADS + t;
                    const uint4 e = tc[k];
                    const uint32_t xm1 = (uint32_t)((int32_t)e.x >> 31);
                    const uint32_t xm2 = (uint32_t)((int32_t)e.z >> 31);
                    const uint32_t xm3 = (uint32_t)((int32_t)e.w >> 31);
                    const uint32_t r0 = ((((uint32_t)A[k] & (uint32_t)B[k]) ^ xm1) &
                                         (((uint32_t)C[k] & (uint32_t)D[k]) ^ xm2)) ^ xm3;
                    const uint32_t r1 = ((((uint32_t)(A[k] >> 32) & (uint32_t)(B[k] >> 32)) ^ xm1) &
                                         (((uint32_t)(C[k] >> 32) & (uint32_t)(D[k] >> 32)) ^ xm2)) ^ xm3;
                    SOA_WRITE2(db0 + (uint32_t)n * 4u, r0, r1);
                }
            } else {                                 // F == 16: last layer Y -> R
                const int n = t;
                const int2 ij = ((const int2*)idx_last)[n];
                const uint32_t xm = mask_last[n] ? 0xFFFFFFFFu : 0u;
                uint64_t a, bb;
                SOA_READ2(a,  Y0B + (uint32_t)ij.x * 4u);
                SOA_READ2(bb, Y0B + (uint32_t)ij.y * 4u);
                asm volatile("s_waitcnt lgkmcnt(0)" ::: "memory");
                __builtin_amdgcn_sched_barrier(0);
                uint2 r;
                r.x = ((uint32_t)a         & (uint32_t)bb)         ^ xm;
                r.y = ((uint32_t)(a >> 32) & (uint32_t)(bb >> 32)) ^ xm;
                *(uint2*)&R[n * 2] = r;
            }

            // ---- (c) unpack 64 rows of previous chunk's result -> global ----
            if (do_unpack && F <= 15) {
                const int ur = F * 64 + wv * 4;
                #pragma unroll
                for (int q = 0; q < 4; ++q) {
                    const uint2 w = *(const uint2*)&R[(ur + q) * 2];  // broadcast
                    const uint32_t sel = (l < 32) ? w.x : w.y;
                    out[(size_t)(ur + q) * W + c0p + l] = (sel >> lane32) & 1u;
                }
            }

            // ---- (d) ballot-commit the pack rows issued at (a) ----
            if (do_pack && F >= 1) {
                #pragma unroll
                for (int q = 0; q < 4; ++q) {
                    const unsigned long long bb = __ballot(pv[q] != 0u);
                    if (l == 0) {
                        uint2 w;
                        w.x = (uint32_t)bb;
                        w.y = (uint32_t)(bb >> 32);
                        *(uint2*)&P[(prow + q) * 2] = w;
                    }
                }
            }

            LIGHT_BARRIER();
        }
    }

    // ---------------- epilogue: unpack last chunk's result ----------------
    {
        const int c0l = (chunk0 + 512 * (CPW - 1)) * CHUNK;
        #pragma unroll 4
        for (int s = 0; s < 16; ++s) {
            #pragma unroll
            for (int q = 0; q < 4; ++q) {
                const int r = s * 64 + wv * 4 + q;
                const uint2 w = *(const uint2*)&R[r * 2];
                const uint32_t sel = (l < 32) ? w.x : w.y;
                out[(size_t)r * W + c0l + l] = (sel >> lane32) & 1u;
            }
        }
    }
}

// ---------------------------------------------------------------------------
// Fallback (R5 kernel, unfused, 128-col) if workspace too small for tables.
// ---------------------------------------------------------------------------
#define FCHUNK  128
#define FWPN    4
#define FGRID   256
#define FCPW    2
__global__ __launch_bounds__(THREADS, 4)
void nand_pipe128_kernel(const uint32_t* __restrict__ in,
                         const int*      __restrict__ idx_first,
                         const uint32_t* __restrict__ mask_first,
                         const int*      __restrict__ idx_mid,
                         const uint32_t* __restrict__ mask_mid,
                         const int*      __restrict__ idx_last,
                         const uint32_t* __restrict__ mask_last,
                         uint32_t*       __restrict__ out)
{
    __shared__ uint32_t lds[40960];
    uint32_t* P = lds;
    uint32_t* X = lds + 4096;
    uint32_t* Y = lds + 20480;
    uint32_t* R = lds + 36864;

    const int t      = threadIdx.x;
    const int l      = t & 63;
    const int wv     = t >> 6;
    const int lane32 = l & 31;
    const int half   = l >> 5;
    const int shift  = half ? 32 : 0;
    const int bcol   = blockIdx.x * (FCPW * FCHUNK);

    #pragma unroll 4
    for (int s = 0; s < 32; ++s) {
        const int r = s * 32 + wv * 2 + half;
        const uint4 v = *(const uint4*)(in + (size_t)r * W + bcol + lane32 * 4);
        const unsigned long long b0 = __ballot(v.x != 0u);
        const unsigned long long b1 = __ballot(v.y != 0u);
        const unsigned long long b2 = __ballot(v.z != 0u);
        const unsigned long long b3 = __ballot(v.w != 0u);
        if (lane32 == 0) {
            uint4 w;
            w.x = (uint32_t)(b0 >> shift);  w.y = (uint32_t)(b1 >> shift);
            w.z = (uint32_t)(b2 >> shift);  w.w = (uint32_t)(b3 >> shift);
            *(uint4*)&P[r * FWPN] = w;
        }
    }
    __syncthreads();

    for (int i = 0; i < FCPW; ++i) {
        const int c0n = bcol + (i + 1) * FCHUNK;
        const int c0p = bcol + (i - 1) * FCHUNK;
        const bool do_pack   = (i + 1 < FCPW);
        const bool do_unpack = (i > 0);

        for (int L = 0; L <= 32; ++L) {
            uint4 pv = {0, 0, 0, 0};
            int   pr = 0;
            if (do_pack && L >= 1) {
                pr = (L - 1) * 32 + wv * 2 + half;
                pv = *(const uint4*)(in + (size_t)pr * W + c0n + lane32 * 4);
            }
            if (L == 0) {
                #pragma unroll
                for (int k = 0; k < NN / THREADS; ++k) {
                    const int n = k * THREADS + t;
                    const int2 ij = ((const int2*)idx_first)[n];
                    const uint32_t xm = mask_first[n] ? 0xFFFFFFFFu : 0u;
                    const uint4 a = *(const uint4*)&P[ij.x * FWPN];
                    const uint4 b = *(const uint4*)&P[ij.y * FWPN];
                    uint4 r;
                    r.x = (a.x & b.x) ^ xm;  r.y = (a.y & b.y) ^ xm;
                    r.z = (a.z & b.z) ^ xm;  r.w = (a.w & b.w) ^ xm;
                    *(uint4*)&X[n * FWPN] = r;
                }
            } else if (L <= 31) {
                const int*      idxL = idx_mid + (size_t)(L - 1) * NN * 2;
                const uint32_t* mL   = mask_mid + (size_t)(L - 1) * NN;
                const uint32_t* src  = (L & 1) ? X : Y;
                uint32_t*       dst  = (L & 1) ? Y : X;
                #pragma unroll
                for (int k = 0; k < NN / THREADS; ++k) {
                    const int n = k * THREADS + t;
                    const int2 ij = ((const int2*)idxL)[n];
                    const uint32_t xm = mL[n] ? 0xFFFFFFFFu : 0u;
                    const uint4 a = *(const uint4*)&src[ij.x * FWPN];
                    const uint4 b = *(const uint4*)&src[ij.y * FWPN];
                    uint4 r;
                    r.x = (a.x & b.x) ^ xm;  r.y = (a.y & b.y) ^ xm;
                    r.z = (a.z & b.z) ^ xm;  r.w = (a.w & b.w) ^ xm;
                    *(uint4*)&dst[n * FWPN] = r;
                }
            } else {
                const int n = t;
                const int2 ij = ((const int2*)idx_last)[n];
                const uint32_t xm = mask_last[n] ? 0xFFFFFFFFu : 0u;
                const uint4 a = *(const uint4*)&Y[ij.x * FWPN];
                const uint4 b = *(const uint4*)&Y[ij.y * FWPN];
                uint4 r;
                r.x = (a.x & b.x) ^ xm;  r.y = (a.y & b.y) ^ xm;
                r.z = (a.z & b.z) ^ xm;  r.w = (a.w & b.w) ^ xm;
                *(uint4*)&R[n * FWPN] = r;
            }
            if (do_unpack && L <= 31) {
                const int r = L * 32 + wv * 2 + half;
                const uint4 w4 = *(const uint4*)&R[r * FWPN];
                uint4 v;
                v.x = (w4.x >> lane32) & 1u;  v.y = (w4.y >> lane32) & 1u;
                v.z = (w4.z >> lane32) & 1u;  v.w = (w4.w >> lane32) & 1u;
                *(uint4*)(out + (size_t)r * W + c0p + lane32 * 4) = v;
            }
            if (do_pack && L >= 1) {
                const unsigned long long b0 = __ballot(pv.x != 0u);
                const unsigned long long b1 = __ballot(pv.y != 0u);
                const unsigned long long b2 = __ballot(pv.z != 0u);
                const unsigned long long b3 = __ballot(pv.w != 0u);
                if (lane32 == 0) {
                    uint4 w;
                    w.x = (uint32_t)(b0 >> shift);  w.y = (uint32_t)(b1 >> shift);
                    w.z = (uint32_t)(b2 >> shift);  w.w = (uint32_t)(b3 >> shift);
                    *(uint4*)&P[pr * FWPN] = w;
                }
            }
            __syncthreads();
        }
    }
    {
        const int c0l = bcol + (FCPW - 1) * FCHUNK;
        #pragma unroll 4
        for (int s = 0; s < 32; ++s) {
            const int r = s * 32 + wv * 2 + half;
            const uint4 w4 = *(const uint4*)&R[r * FWPN];
            uint4 v;
            v.x = (w4.x >> lane32) & 1u;  v.y = (w4.y >> lane32) & 1u;
            v.z = (w4.z >> lane32) & 1u;  v.w = (w4.w >> lane32) & 1u;
            *(uint4*)(out + (size_t)r * W + c0l + lane32 * 4) = v;
        }
    }
}

extern "C" void kernel_launch(void* const* d_in, const int* in_sizes, int n_in,
                              void* d_out, int out_size, void* d_ws, size_t ws_size,
                              hipStream_t stream) {
    const uint32_t* in         = (const uint32_t*)d_in[0];
    const int*      idx_first  = (const int*)d_in[1];
    const uint32_t* mask_first = (const uint32_t*)d_in[2];
    const int*      idx_mid    = (const int*)d_in[3];
    const uint32_t* mask_mid   = (const uint32_t*)d_in[4];
    const int*      idx_last   = (const int*)d_in[5];
    const uint32_t* mask_last  = (const uint32_t*)d_in[6];
    uint32_t*       out        = (uint32_t*)d_out;

    if (ws_size >= TBL_BYTES) {
        uint4* tbl = (uint4*)d_ws;
        build_tbl_kernel<<<(NPAIRS * NN) / 256, 256, 0, stream>>>(
            idx_first, mask_first, idx_mid, mask_mid, tbl);
        nand_fused_kernel<<<GRID, THREADS, 0, stream>>>(
            in, tbl, idx_last, mask_last, out);
    } else {
        nand_pipe128_kernel<<<FGRID, THREADS, 0, stream>>>(
            in, idx_first, mask_first, idx_mid, mask_mid, idx_last, mask_last, out);
    }
}

// Round 15
// 180.013 us; speedup vs baseline: 1.1742x; 1.1742x over previous
//
#include <hip/hip_runtime.h>
#include <stdint.h>

#define NINPUTS   1024
#define NOUTPUTS  1024
#define NMID      31          // middle layers
#define NN        4096        // neurons per layer
#define W         65536       // bit-array width
#define CHUNK     64          // columns per chunk: one 64-bit ballot packs a row
#define NCHUNKS   (W / CHUNK) // 1024
#define GRID      512         // 2 WGs per CU (80 KiB LDS each)
#define CPW       (NCHUNKS / GRID)   // 2 chunks per WG, pipelined
#define THREADS   1024
#define NPAIRS    16          // fused layer-pairs (L0,L1)..(L30,L31); L32 single
#define TBL_BYTES ((size_t)NPAIRS * NN * 16)

// LDS map (80 KiB/WG -> 2 WGs/CU = 32 waves/CU, the HW max):
//   P  AoS uint2 rows (1024 x 8B)   [    0,  8192)
//   X  AoS uint2 rows (4096 x 8B)   [ 8192, 40960)
//   Y  AoS uint2 rows (4096 x 8B)   [40960, 73728)
//   R  AoS uint2 rows (1024 x 8B)   [73728, 81920)
// AoS uint2: row r -> banks (2r, 2r+1) mod 32 = 16 start-classes. Random b64
// gather ~2.2x ideal serialization (multinomial max). SoA/st64 (R14) was
// WORSE (same-bank pairs + 32-class single-dword max ~2.8x) — reverted.
#define PB  0u
#define X0B 8192u
#define Y0B 40960u
#define RB  73728u

// Light barrier (R13: verified correct): orders LDS (lgkmcnt 0) without
// draining vmcnt — global stores/loads stay in flight across rounds.
#define LIGHT_BARRIER() asm volatile("s_waitcnt lgkmcnt(0)\n\ts_barrier" ::: "memory")

// ---------------------------------------------------------------------------
// Prep kernel. Pair F computes layer 2F+1 from layer 2F's input state:
//   r = (((s[a1]&s[b1])^m1) & ((s[a2]&s[b2])^m2)) ^ m3
// All offsets are AoS uint2 byte offsets: row*8 (<= 32760, fits 16 bits).
// Entry: e.x = a1off|m1<<31; e.y = b1off; e.z = a2off|m2<<31; e.w = b2off|m3<<31.
// ---------------------------------------------------------------------------
__global__ void build_tbl_kernel(const int*      __restrict__ idx_first,
                                 const uint32_t* __restrict__ mask_first,
                                 const int*      __restrict__ idx_mid,
                                 const uint32_t* __restrict__ mask_mid,
                                 uint4*          __restrict__ tbl)
{
    const int tid = blockIdx.x * blockDim.x + threadIdx.x;   // 0..65535
    const int F = tid >> 12;
    const int n = tid & (NN - 1);

    const int*      i1;
    const uint32_t* m1;
    if (F == 0) { i1 = idx_first; m1 = mask_first; }
    else        { i1 = idx_mid + (size_t)(2 * F - 1) * NN * 2;
                  m1 = mask_mid + (size_t)(2 * F - 1) * NN; }
    const int*      i2 = idx_mid + (size_t)(2 * F) * NN * 2;
    const uint32_t* m2 = mask_mid + (size_t)(2 * F) * NN;

    const int j = i2[2 * n];
    const int k = i2[2 * n + 1];
    uint4 e;
    e.x = (uint32_t)i1[2 * j]     * 8u | (m1[j] ? 0x80000000u : 0u);
    e.y = (uint32_t)i1[2 * j + 1] * 8u;
    e.z = (uint32_t)i1[2 * k]     * 8u | (m1[k] ? 0x80000000u : 0u);
    e.w = (uint32_t)i1[2 * k + 1] * 8u | (m2[n] ? 0x80000000u : 0u);
    tbl[(size_t)F * NN + n] = e;
}

// ---------------------------------------------------------------------------
// Main kernel: 17 fused rounds/chunk, pipelined pack/unpack (R8 schedule),
// 64-col chunks, AoS uint2 state, 2 WGs/CU (32 waves/CU = HW max — the TLP
// that R8's 1-WG structure lacked; R8's LDS pipe ran ~59% utilized and 6
// ILP-forcing probes failed to fill it).
// XCD pairing (validated R14): blocks b and b^8 share an XCD (%8 round-
// robin); they own the two adjacent 64-col halves of each 512B global block
// so the per-XCD L2 merges their 256B bursts (R4: unpaired 256B bursts
// amplify HBM ~3x; R14 paired: only +8%).
// ---------------------------------------------------------------------------
__global__ __launch_bounds__(THREADS, 8)
void nand_fused_kernel(const uint32_t* __restrict__ in,         // [1024][W]
                       const uint4*    __restrict__ tbl,        // [16][NN]
                       const int*      __restrict__ idx_last,   // [NOUTPUTS][2]
                       const uint32_t* __restrict__ mask_last,  // [NOUTPUTS]
                       uint32_t*       __restrict__ out)        // [NOUTPUTS][W]
{
    __shared__ uint32_t lds[20480];          // 80 KiB
    uint32_t* P = lds;                       // AoS uint2 rows
    uint32_t* X = lds + (X0B / 4);
    uint32_t* Y = lds + (Y0B / 4);
    uint32_t* R = lds + (RB / 4);

    const int t  = threadIdx.x;
    const int l  = t & 63;
    const int wv = t >> 6;                   // wave 0..15
    const int lane32 = l & 31;

    // XCD-paired chunk mapping (bijective, validated R14): b -> (xcd, j, h)
    const int b      = blockIdx.x;
    const int xcd    = b & 7;
    const int jj     = b >> 4;               // 0..31
    const int hh     = (b >> 3) & 1;         // which half of the 512B block
    const int pairid = xcd * 32 + jj;        // 0..255
    const int chunk0 = 2 * pairid + hh;      // phase-0 chunk, 0..511
    // phase-i chunk = chunk0 + 512*i ; c0 = chunk*64

    // ---------------- prologue: pack chunk(0) fully into P ----------------
    {
        const int c0 = chunk0 * CHUNK;
        #pragma unroll 4
        for (int s = 0; s < 16; ++s) {
            #pragma unroll
            for (int q = 0; q < 4; ++q) {
                const int r = s * 64 + wv * 4 + q;
                const uint32_t v = in[(size_t)r * W + c0 + l];
                const unsigned long long bb = __ballot(v != 0u);
                if (l == 0) {
                    uint2 w;
                    w.x = (uint32_t)bb;
                    w.y = (uint32_t)(bb >> 32);
                    *(uint2*)&P[r * 2] = w;
                }
            }
        }
    }
    __syncthreads();

    for (int i = 0; i < CPW; ++i) {
        const int c0n = (chunk0 + 512 * (i + 1)) * CHUNK;   // pack source cols
        const int c0p = (chunk0 + 512 * (i - 1)) * CHUNK;   // unpack dest cols
        const bool do_pack   = (i + 1 < CPW);
        const bool do_unpack = (i > 0);

        for (int F = 0; F <= 16; ++F) {
            // ---- (a) global loads at round top ----
            uint32_t pv[4];
            int prow = 0;
            if (do_pack && F >= 1) {
                prow = (F - 1) * 64 + wv * 4;
                #pragma unroll
                for (int q = 0; q < 4; ++q)
                    pv[q] = in[(size_t)(prow + q) * W + c0n + l];
            }
            uint4 tc[4];
            if (F <= 15) {
                #pragma unroll
                for (int k = 0; k < 4; ++k)
                    tc[k] = tbl[(size_t)F * NN + k * THREADS + t];
            }

            // ---- (b) gather-NAND (plain AoS uint2 reads) ----
            if (F <= 15) {
                const uint32_t* src = (F == 0) ? P : ((F & 1) ? X : Y);
                uint32_t*       dst = (F & 1) ? Y : X;
                uint2 A[4], B[4], C[4], D[4];
                #pragma unroll
                for (int k = 0; k < 4; ++k) {
                    const uint4 e = tc[k];
                    A[k] = *(const uint2*)((const char*)src + (e.x & 0xFFFFu));
                    B[k] = *(const uint2*)((const char*)src + e.y);
                    C[k] = *(const uint2*)((const char*)src + (e.z & 0xFFFFu));
                    D[k] = *(const uint2*)((const char*)src + (e.w & 0xFFFFu));
                }
                #pragma unroll
                for (int k = 0; k < 4; ++k) {
                    const int n = k * THREADS + t;
                    const uint4 e = tc[k];
                    const uint32_t xm1 = (uint32_t)((int32_t)e.x >> 31);
                    const uint32_t xm2 = (uint32_t)((int32_t)e.z >> 31);
                    const uint32_t xm3 = (uint32_t)((int32_t)e.w >> 31);
                    uint2 r;
                    r.x = (((A[k].x & B[k].x) ^ xm1) & ((C[k].x & D[k].x) ^ xm2)) ^ xm3;
                    r.y = (((A[k].y & B[k].y) ^ xm1) & ((C[k].y & D[k].y) ^ xm2)) ^ xm3;
                    *(uint2*)&dst[n * 2] = r;
                }
            } else {                                 // F == 16: last layer Y -> R
                const int n = t;
                const int2 ij = ((const int2*)idx_last)[n];
                const uint32_t xm = mask_last[n] ? 0xFFFFFFFFu : 0u;
                const uint2 a = *(const uint2*)&Y[ij.x * 2];
                const uint2 bb = *(const uint2*)&Y[ij.y * 2];
                uint2 r;
                r.x = (a.x & bb.x) ^ xm;
                r.y = (a.y & bb.y) ^ xm;
                *(uint2*)&R[n * 2] = r;
            }

            // ---- (c) unpack 64 rows of previous chunk's result -> global ----
            if (do_unpack && F <= 15) {
                const int ur = F * 64 + wv * 4;
                #pragma unroll
                for (int q = 0; q < 4; ++q) {
                    const uint2 w = *(const uint2*)&R[(ur + q) * 2];  // broadcast
                    const uint32_t sel = (l < 32) ? w.x : w.y;
                    out[(size_t)(ur + q) * W + c0p + l] = (sel >> lane32) & 1u;
                }
            }

            // ---- (d) ballot-commit the pack rows issued at (a) ----
            if (do_pack && F >= 1) {
                #pragma unroll
                for (int q = 0; q < 4; ++q) {
                    const unsigned long long bb = __ballot(pv[q] != 0u);
                    if (l == 0) {
                        uint2 w;
                        w.x = (uint32_t)bb;
                        w.y = (uint32_t)(bb >> 32);
                        *(uint2*)&P[(prow + q) * 2] = w;
                    }
                }
            }

            LIGHT_BARRIER();
        }
    }

    // ---------------- epilogue: unpack last chunk's result ----------------
    {
        const int c0l = (chunk0 + 512 * (CPW - 1)) * CHUNK;
        #pragma unroll 4
        for (int s = 0; s < 16; ++s) {
            #pragma unroll
            for (int q = 0; q < 4; ++q) {
                const int r = s * 64 + wv * 4 + q;
                const uint2 w = *(const uint2*)&R[r * 2];
                const uint32_t sel = (l < 32) ? w.x : w.y;
                out[(size_t)r * W + c0l + l] = (sel >> lane32) & 1u;
            }
        }
    }
}

// ---------------------------------------------------------------------------
// Fallback (R5 kernel, unfused, 128-col) if workspace too small for tables.
// ---------------------------------------------------------------------------
#define FCHUNK  128
#define FWPN    4
#define FGRID   256
#define FCPW    2
__global__ __launch_bounds__(THREADS, 4)
void nand_pipe128_kernel(const uint32_t* __restrict__ in,
                         const int*      __restrict__ idx_first,
                         const uint32_t* __restrict__ mask_first,
                         const int*      __restrict__ idx_mid,
                         const uint32_t* __restrict__ mask_mid,
                         const int*      __restrict__ idx_last,
                         const uint32_t* __restrict__ mask_last,
                         uint32_t*       __restrict__ out)
{
    __shared__ uint32_t lds[40960];
    uint32_t* P = lds;
    uint32_t* X = lds + 4096;
    uint32_t* Y = lds + 20480;
    uint32_t* R = lds + 36864;

    const int t      = threadIdx.x;
    const int l      = t & 63;
    const int wv     = t >> 6;
    const int lane32 = l & 31;
    const int half   = l >> 5;
    const int shift  = half ? 32 : 0;
    const int bcol   = blockIdx.x * (FCPW * FCHUNK);

    #pragma unroll 4
    for (int s = 0; s < 32; ++s) {
        const int r = s * 32 + wv * 2 + half;
        const uint4 v = *(const uint4*)(in + (size_t)r * W + bcol + lane32 * 4);
        const unsigned long long b0 = __ballot(v.x != 0u);
        const unsigned long long b1 = __ballot(v.y != 0u);
        const unsigned long long b2 = __ballot(v.z != 0u);
        const unsigned long long b3 = __ballot(v.w != 0u);
        if (lane32 == 0) {
            uint4 w;
            w.x = (uint32_t)(b0 >> shift);  w.y = (uint32_t)(b1 >> shift);
            w.z = (uint32_t)(b2 >> shift);  w.w = (uint32_t)(b3 >> shift);
            *(uint4*)&P[r * FWPN] = w;
        }
    }
    __syncthreads();

    for (int i = 0; i < FCPW; ++i) {
        const int c0n = bcol + (i + 1) * FCHUNK;
        const int c0p = bcol + (i - 1) * FCHUNK;
        const bool do_pack   = (i + 1 < FCPW);
        const bool do_unpack = (i > 0);

        for (int L = 0; L <= 32; ++L) {
            uint4 pv = {0, 0, 0, 0};
            int   pr = 0;
            if (do_pack && L >= 1) {
                pr = (L - 1) * 32 + wv * 2 + half;
                pv = *(const uint4*)(in + (size_t)pr * W + c0n + lane32 * 4);
            }
            if (L == 0) {
                #pragma unroll
                for (int k = 0; k < NN / THREADS; ++k) {
                    const int n = k * THREADS + t;
                    const int2 ij = ((const int2*)idx_first)[n];
                    const uint32_t xm = mask_first[n] ? 0xFFFFFFFFu : 0u;
                    const uint4 a = *(const uint4*)&P[ij.x * FWPN];
                    const uint4 b = *(const uint4*)&P[ij.y * FWPN];
                    uint4 r;
                    r.x = (a.x & b.x) ^ xm;  r.y = (a.y & b.y) ^ xm;
                    r.z = (a.z & b.z) ^ xm;  r.w = (a.w & b.w) ^ xm;
                    *(uint4*)&X[n * FWPN] = r;
                }
            } else if (L <= 31) {
                const int*      idxL = idx_mid + (size_t)(L - 1) * NN * 2;
                const uint32_t* mL   = mask_mid + (size_t)(L - 1) * NN;
                const uint32_t* src  = (L & 1) ? X : Y;
                uint32_t*       dst  = (L & 1) ? Y : X;
                #pragma unroll
                for (int k = 0; k < NN / THREADS; ++k) {
                    const int n = k * THREADS + t;
                    const int2 ij = ((const int2*)idxL)[n];
                    const uint32_t xm = mL[n] ? 0xFFFFFFFFu : 0u;
                    const uint4 a = *(const uint4*)&src[ij.x * FWPN];
                    const uint4 b = *(const uint4*)&src[ij.y * FWPN];
                    uint4 r;
                    r.x = (a.x & b.x) ^ xm;  r.y = (a.y & b.y) ^ xm;
                    r.z = (a.z & b.z) ^ xm;  r.w = (a.w & b.w) ^ xm;
                    *(uint4*)&dst[n * FWPN] = r;
                }
            } else {
                const int n = t;
                const int2 ij = ((const int2*)idx_last)[n];
                const uint32_t xm = mask_last[n] ? 0xFFFFFFFFu : 0u;
                const uint4 a = *(const uint4*)&Y[ij.x * FWPN];
                const uint4 b = *(const uint4*)&Y[ij.y * FWPN];
                uint4 r;
                r.x = (a.x & b.x) ^ xm;  r.y = (a.y & b.y) ^ xm;
                r.z = (a.z & b.z) ^ xm;  r.w = (a.w & b.w) ^ xm;
                *(uint4*)&R[n * FWPN] = r;
            }
            if (do_unpack && L <= 31) {
                const int r = L * 32 + wv * 2 + half;
                const uint4 w4 = *(const uint4*)&R[r * FWPN];
                uint4 v;
                v.x = (w4.x >> lane32) & 1u;  v.y = (w4.y >> lane32) & 1u;
                v.z = (w4.z >> lane32) & 1u;  v.w = (w4.w >> lane32) & 1u;
                *(uint4*)(out + (size_t)r * W + c0p + lane32 * 4) = v;
            }
            if (do_pack && L >= 1) {
                const unsigned long long b0 = __ballot(pv.x != 0u);
                const unsigned long long b1 = __ballot(pv.y != 0u);
                const unsigned long long b2 = __ballot(pv.z != 0u);
                const unsigned long long b3 = __ballot(pv.w != 0u);
                if (lane32 == 0) {
                    uint4 w;
                    w.x = (uint32_t)(b0 >> shift);  w.y = (uint32_t)(b1 >> shift);
                    w.z = (uint32_t)(b2 >> shift);  w.w = (uint32_t)(b3 >> shift);
                    *(uint4*)&P[pr * FWPN] = w;
                }
            }
            __syncthreads();
        }
    }
    {
        const int c0l = bcol + (FCPW - 1) * FCHUNK;
        #pragma unroll 4
        for (int s = 0; s < 32; ++s) {
            const int r = s * 32 + wv * 2 + half;
            const uint4 w4 = *(const uint4*)&R[r * FWPN];
            uint4 v;
            v.x = (w4.x >> lane32) & 1u;  v.y = (w4.y >> lane32) & 1u;
            v.z = (w4.z >> lane32) & 1u;  v.w = (w4.w >> lane32) & 1u;
            *(uint4*)(out + (size_t)r * W + c0l + lane32 * 4) = v;
        }
    }
}

extern "C" void kernel_launch(void* const* d_in, const int* in_sizes, int n_in,
                              void* d_out, int out_size, void* d_ws, size_t ws_size,
                              hipStream_t stream) {
    const uint32_t* in         = (const uint32_t*)d_in[0];
    const int*      idx_first  = (const int*)d_in[1];
    const uint32_t* mask_first = (const uint32_t*)d_in[2];
    const int*      idx_mid    = (const int*)d_in[3];
    const uint32_t* mask_mid   = (const uint32_t*)d_in[4];
    const int*      idx_last   = (const int*)d_in[5];
    const uint32_t* mask_last  = (const uint32_t*)d_in[6];
    uint32_t*       out        = (uint32_t*)d_out;

    if (ws_size >= TBL_BYTES) {
        uint4* tbl = (uint4*)d_ws;
        build_tbl_kernel<<<(NPAIRS * NN) / 256, 256, 0, stream>>>(
            idx_first, mask_first, idx_mid, mask_mid, tbl);
        nand_fused_kernel<<<GRID, THREADS, 0, stream>>>(
            in, tbl, idx_last, mask_last, out);
    } else {
        nand_pipe128_kernel<<<FGRID, THREADS, 0, stream>>>(
            in, idx_first, mask_first, idx_mid, mask_mid, idx_last, mask_last, out);
    }
}

// Round 16
// 151.810 us; speedup vs baseline: 1.3923x; 1.1858x over previous
//
#include <hip/hip_runtime.h>
#include <stdint.h>

#define NINPUTS   1024
#define NOUTPUTS  1024
#define NMID      31          // middle layers
#define NN        4096        // neurons per layer
#define W         65536       // bit-array width
#define CHUNK     128         // columns per chunk (512-B rows: min clean HBM granule)
#define WPN       4           // u32 words per row (CHUNK/32)
#define NCHUNKS   (W / CHUNK) // 512
#define GRID      256         // 1 WG per CU
#define CPW       (NCHUNKS / GRID)   // 2 chunks per WG, pipelined
#define THREADS   1024
#define NPAIRS    16          // fused layer-pairs (L0,L1)..(L30,L31); L32 single
#define TBL_BYTES ((size_t)NPAIRS * NN * 16)

// ---------------------------------------------------------------------------
// BEST CONFIG (R8, 151.9 us) — restored after R9-R15 probes all regressed or
// were null. Established across the session:
//  * CHUNK=128 b128-AoS beats all alternatives (b64/2WG: op-count tax, R15;
//    SoA/st64: same-bank pairs + multinomial max, R10/R14; class-sort: R7).
//  * Allocator hard-caps this kernel at 64 VGPR (launch_bounds ignored, R12)
//    -> deep read batching impossible (R11 spilled, R9 re-serialized).
//  * Barrier vmcnt drain is not the cost (R13 null).
//  * 2-layer fusion is the optimal depth (reads = 2^k per k fused layers).
// Remaining gap to ideal (~110us) is latency-structural at 4 waves/SIMD with
// 160KB LDS (1 WG/CU) — unreachable without >64 VGPR or >160KB LDS.
// ---------------------------------------------------------------------------

// Prep kernel (identity order). Pair F computes layer 2F+1 from layer 2F's
// input state:  r = (((s[a1]&s[b1])^m1) & ((s[a2]&s[b2])^m2)) ^ m3
// Entry: e.x = a1*16 | m1<<31; e.y = b1*16;
//        e.z = a2*16 | m2<<31; e.w = b2*16 | m3<<31.   (byte offsets <= 65520)
__global__ void build_tbl_kernel(const int*      __restrict__ idx_first,
                                 const uint32_t* __restrict__ mask_first,
                                 const int*      __restrict__ idx_mid,
                                 const uint32_t* __restrict__ mask_mid,
                                 uint4*          __restrict__ tbl)
{
    const int tid = blockIdx.x * blockDim.x + threadIdx.x;   // 0..65535
    const int F = tid >> 12;
    const int n = tid & (NN - 1);

    const int*      i1;
    const uint32_t* m1;
    if (F == 0) { i1 = idx_first; m1 = mask_first; }
    else        { i1 = idx_mid + (size_t)(2 * F - 1) * NN * 2;
                  m1 = mask_mid + (size_t)(2 * F - 1) * NN; }
    const int*      i2 = idx_mid + (size_t)(2 * F) * NN * 2;
    const uint32_t* m2 = mask_mid + (size_t)(2 * F) * NN;

    const int j = i2[2 * n];
    const int k = i2[2 * n + 1];
    uint4 e;
    e.x = (uint32_t)(i1[2 * j]     * 16) | (m1[j] ? 0x80000000u : 0u);
    e.y = (uint32_t)(i1[2 * j + 1] * 16);
    e.z = (uint32_t)(i1[2 * k]     * 16) | (m1[k] ? 0x80000000u : 0u);
    e.w = (uint32_t)(i1[2 * k + 1] * 16) | (m2[n] ? 0x80000000u : 0u);
    tbl[(size_t)F * NN + n] = e;
}

// Main kernel: 17 rounds/chunk (16 fused pairs + last layer), pipelined
// pack/unpack, register table prefetch, batched gather reads.
// LDS 160 KiB: P (16K) | X (64K) | Y (64K) | R (16K).
__global__ __launch_bounds__(THREADS, 4)
void nand_fused_kernel(const uint32_t* __restrict__ in,         // [1024][W]
                       const uint4*    __restrict__ tbl,        // [16][NN]
                       const int*      __restrict__ idx_last,   // [NOUTPUTS][2]
                       const uint32_t* __restrict__ mask_last,  // [NOUTPUTS]
                       uint32_t*       __restrict__ out)        // [NOUTPUTS][W]
{
    __shared__ uint32_t lds[40960];          // 160 KiB exactly
    uint32_t* P = lds;                       // 1024 * 4 dwords (16 KB)
    uint32_t* X = lds + 4096;                // 4096 * 4 dwords (64 KB)
    uint32_t* Y = lds + 20480;               // 4096 * 4 dwords (64 KB)
    uint32_t* R = lds + 36864;               // 1024 * 4 dwords (16 KB)

    const int t      = threadIdx.x;
    const int l      = t & 63;
    const int wv     = t >> 6;               // wave 0..15
    const int lane32 = l & 31;
    const int half   = l >> 5;
    const int shift  = half ? 32 : 0;
    const int bcol   = blockIdx.x * (CPW * CHUNK);

    // ---------------- prologue: pack chunk 0 fully into P ----------------
    #pragma unroll 4
    for (int s = 0; s < 32; ++s) {
        const int r = s * 32 + wv * 2 + half;
        const uint4 v = *(const uint4*)(in + (size_t)r * W + bcol + lane32 * 4);
        const unsigned long long b0 = __ballot(v.x != 0u);
        const unsigned long long b1 = __ballot(v.y != 0u);
        const unsigned long long b2 = __ballot(v.z != 0u);
        const unsigned long long b3 = __ballot(v.w != 0u);
        if (lane32 == 0) {
            uint4 w;
            w.x = (uint32_t)(b0 >> shift);
            w.y = (uint32_t)(b1 >> shift);
            w.z = (uint32_t)(b2 >> shift);
            w.w = (uint32_t)(b3 >> shift);
            *(uint4*)&P[r * WPN] = w;
        }
    }
    __syncthreads();

    for (int i = 0; i < CPW; ++i) {
        const int c0n = bcol + (i + 1) * CHUNK;      // pack source cols
        const int c0p = bcol + (i - 1) * CHUNK;      // unpack dest cols
        const bool do_pack   = (i + 1 < CPW);
        const bool do_unpack = (i > 0);

        // cold-load round-0 table entries for this chunk
        uint4 tc[4], tn[4];
        #pragma unroll
        for (int k = 0; k < 4; ++k) tc[k] = tbl[k * THREADS + t];

        for (int F = 0; F <= 16; ++F) {
            // ---- (a) issue global loads at round top ----
            uint4 pv0 = {0,0,0,0}, pv1 = {0,0,0,0};
            int pr0 = 0, pr1 = 0;
            if (do_pack && F >= 1) {
                pr0 = (F - 1) * 64 + wv * 2 + half;
                pr1 = pr0 + 32;
                pv0 = *(const uint4*)(in + (size_t)pr0 * W + c0n + lane32 * 4);
                pv1 = *(const uint4*)(in + (size_t)pr1 * W + c0n + lane32 * 4);
            }

            // ---- (b) fused gather-NAND: batched reads, then compute+write ----
            if (F <= 15) {
                const uint32_t* src = (F == 0) ? P : ((F & 1) ? X : Y);
                uint32_t*       dst = (F & 1) ? Y : X;
                uint4 A[4], B[4], C[4], D[4];
                #pragma unroll
                for (int k = 0; k < 4; ++k) {
                    const uint4 e = tc[k];
                    A[k] = *(const uint4*)((const char*)src + (e.x & 0xFFFFu));
                    B[k] = *(const uint4*)((const char*)src + e.y);
                    C[k] = *(const uint4*)((const char*)src + (e.z & 0xFFFFu));
                    D[k] = *(const uint4*)((const char*)src + (e.w & 0xFFFFu));
                }
                #pragma unroll
                for (int k = 0; k < 4; ++k) {
                    const int n = k * THREADS + t;
                    const uint4 e = tc[k];
                    const uint32_t xm1 = (uint32_t)((int32_t)e.x >> 31);
                    const uint32_t xm2 = (uint32_t)((int32_t)e.z >> 31);
                    const uint32_t xm3 = (uint32_t)((int32_t)e.w >> 31);
                    uint4 r;
                    r.x = (((A[k].x & B[k].x) ^ xm1) & ((C[k].x & D[k].x) ^ xm2)) ^ xm3;
                    r.y = (((A[k].y & B[k].y) ^ xm1) & ((C[k].y & D[k].y) ^ xm2)) ^ xm3;
                    r.z = (((A[k].z & B[k].z) ^ xm1) & ((C[k].z & D[k].z) ^ xm2)) ^ xm3;
                    r.w = (((A[k].w & B[k].w) ^ xm1) & ((C[k].w & D[k].w) ^ xm2)) ^ xm3;
                    *(uint4*)&dst[n * WPN] = r;
                }
            } else {                                 // F == 16: last layer Y -> R
                const int n = t;
                const int2 ij = ((const int2*)idx_last)[n];
                const uint32_t xm = mask_last[n] ? 0xFFFFFFFFu : 0u;
                const uint4 a = *(const uint4*)&Y[ij.x * WPN];
                const uint4 b = *(const uint4*)&Y[ij.y * WPN];
                uint4 r;
                r.x = (a.x & b.x) ^ xm;  r.y = (a.y & b.y) ^ xm;
                r.z = (a.z & b.z) ^ xm;  r.w = (a.w & b.w) ^ xm;
                *(uint4*)&R[n * WPN] = r;
            }

            // ---- (a') prefetch next round's table entries (L2-hot) ----
            if (F <= 14) {
                #pragma unroll
                for (int k = 0; k < 4; ++k)
                    tn[k] = tbl[(size_t)(F + 1) * NN + k * THREADS + t];
            }

            // ---- (c) unpack 64 rows of previous chunk's result -> global ----
            if (do_unpack && F <= 15) {
                #pragma unroll
                for (int s = 0; s < 2; ++s) {
                    const int r = F * 64 + s * 32 + wv * 2 + half;
                    const uint4 w4 = *(const uint4*)&R[r * WPN];
                    uint4 v;
                    v.x = (w4.x >> lane32) & 1u;
                    v.y = (w4.y >> lane32) & 1u;
                    v.z = (w4.z >> lane32) & 1u;
                    v.w = (w4.w >> lane32) & 1u;
                    *(uint4*)(out + (size_t)r * W + c0p + lane32 * 4) = v;
                }
            }

            // ---- (d) ballot-commit the pack rows issued at (a) ----
            if (do_pack && F >= 1) {
                {
                    const unsigned long long b0 = __ballot(pv0.x != 0u);
                    const unsigned long long b1 = __ballot(pv0.y != 0u);
                    const unsigned long long b2 = __ballot(pv0.z != 0u);
                    const unsigned long long b3 = __ballot(pv0.w != 0u);
                    if (lane32 == 0) {
                        uint4 w;
                        w.x = (uint32_t)(b0 >> shift);
                        w.y = (uint32_t)(b1 >> shift);
                        w.z = (uint32_t)(b2 >> shift);
                        w.w = (uint32_t)(b3 >> shift);
                        *(uint4*)&P[pr0 * WPN] = w;
                    }
                }
                {
                    const unsigned long long b0 = __ballot(pv1.x != 0u);
                    const unsigned long long b1 = __ballot(pv1.y != 0u);
                    const unsigned long long b2 = __ballot(pv1.z != 0u);
                    const unsigned long long b3 = __ballot(pv1.w != 0u);
                    if (lane32 == 0) {
                        uint4 w;
                        w.x = (uint32_t)(b0 >> shift);
                        w.y = (uint32_t)(b1 >> shift);
                        w.z = (uint32_t)(b2 >> shift);
                        w.w = (uint32_t)(b3 >> shift);
                        *(uint4*)&P[pr1 * WPN] = w;
                    }
                }
            }

            if (F <= 14) {
                #pragma unroll
                for (int k = 0; k < 4; ++k) tc[k] = tn[k];
            }
            __syncthreads();
        }
    }

    // ---------------- epilogue: unpack last chunk's result ----------------
    {
        const int c0l = bcol + (CPW - 1) * CHUNK;
        #pragma unroll 4
        for (int s = 0; s < 32; ++s) {
            const int r = s * 32 + wv * 2 + half;
            const uint4 w4 = *(const uint4*)&R[r * WPN];
            uint4 v;
            v.x = (w4.x >> lane32) & 1u;
            v.y = (w4.y >> lane32) & 1u;
            v.z = (w4.z >> lane32) & 1u;
            v.w = (w4.w >> lane32) & 1u;
            *(uint4*)(out + (size_t)r * W + c0l + lane32 * 4) = v;
        }
    }
}

// ---------------------------------------------------------------------------
// Fallback (R5 kernel, unfused) if workspace is too small for the tables.
// ---------------------------------------------------------------------------
__global__ __launch_bounds__(THREADS, 4)
void nand_pipe128_kernel(const uint32_t* __restrict__ in,
                         const int*      __restrict__ idx_first,
                         const uint32_t* __restrict__ mask_first,
                         const int*      __restrict__ idx_mid,
                         const uint32_t* __restrict__ mask_mid,
                         const int*      __restrict__ idx_last,
                         const uint32_t* __restrict__ mask_last,
                         uint32_t*       __restrict__ out)
{
    __shared__ uint32_t lds[40960];
    uint32_t* P = lds;
    uint32_t* X = lds + 4096;
    uint32_t* Y = lds + 20480;
    uint32_t* R = lds + 36864;

    const int t      = threadIdx.x;
    const int l      = t & 63;
    const int wv     = t >> 6;
    const int lane32 = l & 31;
    const int half   = l >> 5;
    const int shift  = half ? 32 : 0;
    const int bcol   = blockIdx.x * (CPW * CHUNK);

    #pragma unroll 4
    for (int s = 0; s < 32; ++s) {
        const int r = s * 32 + wv * 2 + half;
        const uint4 v = *(const uint4*)(in + (size_t)r * W + bcol + lane32 * 4);
        const unsigned long long b0 = __ballot(v.x != 0u);
        const unsigned long long b1 = __ballot(v.y != 0u);
        const unsigned long long b2 = __ballot(v.z != 0u);
        const unsigned long long b3 = __ballot(v.w != 0u);
        if (lane32 == 0) {
            uint4 w;
            w.x = (uint32_t)(b0 >> shift);  w.y = (uint32_t)(b1 >> shift);
            w.z = (uint32_t)(b2 >> shift);  w.w = (uint32_t)(b3 >> shift);
            *(uint4*)&P[r * WPN] = w;
        }
    }
    __syncthreads();

    for (int i = 0; i < CPW; ++i) {
        const int c0n = bcol + (i + 1) * CHUNK;
        const int c0p = bcol + (i - 1) * CHUNK;
        const bool do_pack   = (i + 1 < CPW);
        const bool do_unpack = (i > 0);

        for (int L = 0; L <= 32; ++L) {
            uint4 pv = {0, 0, 0, 0};
            int   pr = 0;
            if (do_pack && L >= 1) {
                pr = (L - 1) * 32 + wv * 2 + half;
                pv = *(const uint4*)(in + (size_t)pr * W + c0n + lane32 * 4);
            }
            if (L == 0) {
                #pragma unroll
                for (int k = 0; k < NN / THREADS; ++k) {
                    const int n = k * THREADS + t;
                    const int2 ij = ((const int2*)idx_first)[n];
                    const uint32_t xm = mask_first[n] ? 0xFFFFFFFFu : 0u;
                    const uint4 a = *(const uint4*)&P[ij.x * WPN];
                    const uint4 b = *(const uint4*)&P[ij.y * WPN];
                    uint4 r;
                    r.x = (a.x & b.x) ^ xm;  r.y = (a.y & b.y) ^ xm;
                    r.z = (a.z & b.z) ^ xm;  r.w = (a.w & b.w) ^ xm;
                    *(uint4*)&X[n * WPN] = r;
                }
            } else if (L <= 31) {
                const int*      idxL = idx_mid + (size_t)(L - 1) * NN * 2;
                const uint32_t* mL   = mask_mid + (size_t)(L - 1) * NN;
                const uint32_t* src  = (L & 1) ? X : Y;
                uint32_t*       dst  = (L & 1) ? Y : X;
                #pragma unroll
                for (int k = 0; k < NN / THREADS; ++k) {
                    const int n = k * THREADS + t;
                    const int2 ij = ((const int2*)idxL)[n];
                    const uint32_t xm = mL[n] ? 0xFFFFFFFFu : 0u;
                    const uint4 a = *(const uint4*)&src[ij.x * WPN];
                    const uint4 b = *(const uint4*)&src[ij.y * WPN];
                    uint4 r;
                    r.x = (a.x & b.x) ^ xm;  r.y = (a.y & b.y) ^ xm;
                    r.z = (a.z & b.z) ^ xm;  r.w = (a.w & b.w) ^ xm;
                    *(uint4*)&dst[n * WPN] = r;
                }
            } else {
                const int n = t;
                const int2 ij = ((const int2*)idx_last)[n];
                const uint32_t xm = mask_last[n] ? 0xFFFFFFFFu : 0u;
                const uint4 a = *(const uint4*)&Y[ij.x * WPN];
                const uint4 b = *(const uint4*)&Y[ij.y * WPN];
                uint4 r;
                r.x = (a.x & b.x) ^ xm;  r.y = (a.y & b.y) ^ xm;
                r.z = (a.z & b.z) ^ xm;  r.w = (a.w & b.w) ^ xm;
                *(uint4*)&R[n * WPN] = r;
            }
            if (do_unpack && L <= 31) {
                const int r = L * 32 + wv * 2 + half;
                const uint4 w4 = *(const uint4*)&R[r * WPN];
                uint4 v;
                v.x = (w4.x >> lane32) & 1u;  v.y = (w4.y >> lane32) & 1u;
                v.z = (w4.z >> lane32) & 1u;  v.w = (w4.w >> lane32) & 1u;
                *(uint4*)(out + (size_t)r * W + c0p + lane32 * 4) = v;
            }
            if (do_pack && L >= 1) {
                const unsigned long long b0 = __ballot(pv.x != 0u);
                const unsigned long long b1 = __ballot(pv.y != 0u);
                const unsigned long long b2 = __ballot(pv.z != 0u);
                const unsigned long long b3 = __ballot(pv.w != 0u);
                if (lane32 == 0) {
                    uint4 w;
                    w.x = (uint32_t)(b0 >> shift);  w.y = (uint32_t)(b1 >> shift);
                    w.z = (uint32_t)(b2 >> shift);  w.w = (uint32_t)(b3 >> shift);
                    *(uint4*)&P[pr * WPN] = w;
                }
            }
            __syncthreads();
        }
    }
    {
        const int c0l = bcol + (CPW - 1) * CHUNK;
        #pragma unroll 4
        for (int s = 0; s < 32; ++s) {
            const int r = s * 32 + wv * 2 + half;
            const uint4 w4 = *(const uint4*)&R[r * WPN];
            uint4 v;
            v.x = (w4.x >> lane32) & 1u;  v.y = (w4.y >> lane32) & 1u;
            v.z = (w4.z >> lane32) & 1u;  v.w = (w4.w >> lane32) & 1u;
            *(uint4*)(out + (size_t)r * W + c0l + lane32 * 4) = v;
        }
    }
}

extern "C" void kernel_launch(void* const* d_in, const int* in_sizes, int n_in,
                              void* d_out, int out_size, void* d_ws, size_t ws_size,
                              hipStream_t stream) {
    const uint32_t* in         = (const uint32_t*)d_in[0];
    const int*      idx_first  = (const int*)d_in[1];
    const uint32_t* mask_first = (const uint32_t*)d_in[2];
    const int*      idx_mid    = (const int*)d_in[3];
    const uint32_t* mask_mid   = (const uint32_t*)d_in[4];
    const int*      idx_last   = (const int*)d_in[5];
    const uint32_t* mask_last  = (const uint32_t*)d_in[6];
    uint32_t*       out        = (uint32_t*)d_out;

    if (ws_size >= TBL_BYTES) {
        uint4* tbl = (uint4*)d_ws;
        build_tbl_kernel<<<(NPAIRS * NN) / 256, 256, 0, stream>>>(
            idx_first, mask_first, idx_mid, mask_mid, tbl);
        nand_fused_kernel<<<GRID, THREADS, 0, stream>>>(
            in, tbl, idx_last, mask_last, out);
    } else {
        nand_pipe128_kernel<<<GRID, THREADS, 0, stream>>>(
            in, idx_first, mask_first, idx_mid, mask_mid, idx_last, mask_last, out);
    }
}